// Round 8
// baseline (242.390 us; speedup 1.0000x reference)
//
#include <hip/hip_runtime.h>
#include <stdint.h>

// Problem constants (match reference)
#define T_TOK 1024
#define HDIM  1024
#define IDIM  512
#define NEXP  16
#define ISH   1024       // shared intermediate
#define MAXT64   96      // 64-row routed tiles (gu):  sum pad128(c)/64  <= 96
#define MAXT128  48      // 128-row routed tiles (down)
#define HSLOTS   6144    // 48 * 128 padded routed rows

typedef _Float16 f16;
typedef __attribute__((ext_vector_type(8))) _Float16 f16x8;
typedef __attribute__((ext_vector_type(4))) _Float16 f16x4;
typedef __attribute__((ext_vector_type(4))) float    f32x4;

// ---- async global->LDS, 16B per lane. LDS dst is wave-uniform base; HW adds lane*16.
__device__ __forceinline__ void gld16(const void* g, void* l) {
  __builtin_amdgcn_global_load_lds(
      (__attribute__((address_space(1))) void*)(uintptr_t)g,
      (__attribute__((address_space(3))) void*)(uint32_t)(uintptr_t)l,
      16, 0, 0);
}
// raw barrier: NO vmcnt/lgkm drain -> prefetch loads stay in flight across it
__device__ __forceinline__ void barrier_raw()  { __builtin_amdgcn_s_barrier(); }
// full barrier: drain everything, then barrier (== __syncthreads semantics)
__device__ __forceinline__ void barrier_full() {
  __builtin_amdgcn_s_waitcnt(0);
  __builtin_amdgcn_s_barrier();
}

// ---- A-tile LDS: rows of 64 halfs, 16B chunks XOR-swizzled by (row&7) (gld16-compatible)
__device__ __forceinline__ f16x8 ldsfragA(const f16* buf, int row, int lch) {
  int phys = lch ^ (row & 7);
  return *(const f16x8*)(buf + row * 64 + phys * 8);
}
// ---- B-tile LDS: n-rows of 64 halfs k-contig, stride 72 f16, chunk XOR by (n>>3)&7
__device__ __forceinline__ f16x8 ldsfragB(const f16* buf, int n, int kc) {
  int c = kc ^ ((n >> 3) & 7);
  return *(const f16x8*)(buf + n * 72 + c * 8);
}
// B staging split for pipelining: load fp32 [K,N] tile into regs / cvt+write LDS
__device__ __forceinline__ void loadB(const float* __restrict__ W, int ldW,
                                      int kt, int n0, int tid, float2 v[8]) {
  int p = tid & 31, kg = tid >> 5;            // p: n-pair, kg: k-oct
  const float* src = W + (size_t)(kt + 8 * kg) * ldW + n0 + 2 * p;
#pragma unroll
  for (int r = 0; r < 8; r++) v[r] = *(const float2*)(src + (size_t)r * ldW);
}
__device__ __forceinline__ void writeB(const float2 v[8], f16* __restrict__ Bs, int tid) {
  int p = tid & 31, kg = tid >> 5;
  f16x8 c0, c1;
#pragma unroll
  for (int r = 0; r < 8; r++) { c0[r] = (f16)v[r].x; c1[r] = (f16)v[r].y; }
  int nn = 2 * p;
  int cc = kg ^ ((nn >> 3) & 7);
  *(f16x8*)(Bs + nn * 72 + cc * 8) = c0;
  *(f16x8*)(Bs + (nn + 1) * 72 + cc * 8) = c1;
}

// =============== router GEMV (also emits xh = f16(x)): 4 tokens/block ===============
__global__ __launch_bounds__(256) void router_kernel(
    const float* __restrict__ x, const float* __restrict__ rw, const float* __restrict__ ebias,
    f16* __restrict__ xh, int* __restrict__ topk_i, float* __restrict__ topk_w) {
  int wave = threadIdx.x >> 6, l = threadIdx.x & 63;
  int t = blockIdx.x * 4 + wave;
  float acc[16];
#pragma unroll
  for (int e = 0; e < 16; e++) acc[e] = 0.f;
#pragma unroll
  for (int i = 0; i < 4; i++) {
    int k = i * 256 + l * 4;
    float4 xv = *(const float4*)(x + (size_t)t * HDIM + k);
    f16x4 h = { (f16)xv.x, (f16)xv.y, (f16)xv.z, (f16)xv.w };
    *(f16x4*)(xh + (size_t)t * HDIM + k) = h;
    const float* xp = &xv.x;
#pragma unroll
    for (int j = 0; j < 4; j++) {
      float xj = xp[j];
      const float4* w4 = (const float4*)(rw + (size_t)(k + j) * 16);
#pragma unroll
      for (int q = 0; q < 4; q++) {
        float4 w = w4[q];
        acc[q*4+0] += xj * w.x; acc[q*4+1] += xj * w.y;
        acc[q*4+2] += xj * w.z; acc[q*4+3] += xj * w.w;
      }
    }
  }
#pragma unroll
  for (int off = 32; off >= 1; off >>= 1)
#pragma unroll
    for (int e = 0; e < 16; e++) acc[e] += __shfl_xor(acc[e], off, 64);

  if (l == 0) {
    float s[16], sc[16];
#pragma unroll
    for (int e = 0; e < 16; e++) {
      s[e] = 1.f / (1.f + __expf(-acc[e]));       // sigmoid scores (weights)
      sc[e] = s[e] + ebias[e];                     // biased (selection only)
    }
    float gs[4];
#pragma unroll
    for (int g = 0; g < 4; g++) {                  // sum of top-2 per group of 4
      float a = -1e30f, b2 = -1e30f;
#pragma unroll
      for (int j = 0; j < 4; j++) {
        float v = sc[g*4 + j];
        if (v > a) { b2 = a; a = v; } else if (v > b2) { b2 = v; }
      }
      gs[g] = a + b2;
    }
    int g1 = 0;
    for (int g = 1; g < 4; g++) if (gs[g] > gs[g1]) g1 = g;   // ties -> lowest idx
    int g2 = -1;
    for (int g = 0; g < 4; g++) if (g != g1 && (g2 < 0 || gs[g] > gs[g2])) g2 = g;
    float masked[16];
#pragma unroll
    for (int e = 0; e < 16; e++) {
      int g = e >> 2;
      masked[e] = (g == g1 || g == g2) ? sc[e] : 0.0f;        // ref: unselected -> 0.0
    }
    int idx[4]; float wv[4]; float denom = 1e-20f;
#pragma unroll
    for (int j = 0; j < 4; j++) {
      int best = 0; float bv = masked[0];
      for (int e = 1; e < 16; e++) if (masked[e] > bv) { bv = masked[e]; best = e; }
      idx[j] = best; wv[j] = s[best]; denom += s[best];
      masked[best] = -1e30f;
    }
#pragma unroll
    for (int j = 0; j < 4; j++) {
      topk_i[t * 4 + j] = idx[j];
      topk_w[t * 4 + j] = wv[j] / denom * 2.5f;   // fold ROUTED_SCALE
    }
  }
}

// =============== scatter: lists padded to 128; emits 64-row AND 128-row tiles ===============
__global__ __launch_bounds__(1024) void scatter_kernel(
    const int* __restrict__ tki,
    int* __restrict__ tok, int* __restrict__ slotmap,
    int* __restrict__ t64_e, int* __restrict__ t64_srow, int* __restrict__ t64_hb,
    int* __restrict__ t128_e, int* __restrict__ t128_srow, int* __restrict__ t128_hb,
    int* __restrict__ ntl) {
  __shared__ int lcnt[NEXP], lpos[NEXP], lbase[NEXP];
  int t = threadIdx.x;                   // one thread per token
  if (t < NEXP) { lcnt[t] = 0; lpos[t] = 0; }
  __syncthreads();
  int idx[4];
#pragma unroll
  for (int j = 0; j < 4; j++) idx[j] = tki[t*4+j];
#pragma unroll
  for (int j = 0; j < 4; j++) atomicAdd(&lcnt[idx[j]], 1);
  __syncthreads();
  if (t == 0) {                          // tile metadata (tiny serial)
    int n64 = 0, n128 = 0, slots = 0;
    for (int e = 0; e < NEXP; e++) {
      int c = lcnt[e], top = ((c + 127) >> 7) << 7;
      lbase[e] = slots;
      for (int j = 0; j < top / 64; j++) {
        t64_e[n64] = e; t64_srow[n64] = j * 64; t64_hb[n64] = slots + j * 64; n64++;
      }
      for (int j = 0; j < top / 128; j++) {
        t128_e[n128] = e; t128_srow[n128] = j * 128; t128_hb[n128] = slots + j * 128; n128++;
      }
      slots += top;
    }
    ntl[0] = n64; ntl[1] = n128;
  }
  __syncthreads();
#pragma unroll
  for (int j = 0; j < 4; j++) {
    int slot = atomicAdd(&lpos[idx[j]], 1);
    tok[idx[j] * T_TOK + slot] = t;
    slotmap[t * 4 + j] = lbase[idx[j]] + slot;   // hbuf/odown row of this assignment
  }
  __syncthreads();
  // padding rows (up to 127/expert) gather token 0; results never read by combine
  int e = t >> 6, s = t & 63;
  int c = lcnt[e];
  int top = ((c + 127) >> 7) << 7;
  for (int s2 = c + s; s2 < top; s2 += 64) tok[e * T_TOK + s2] = 0;
}

// =============== GEMM cores ===============
__device__ __forceinline__ f32x4 mfma16(f16x8 a, f16x8 b, f32x4 c) {
  return __builtin_amdgcn_mfma_f32_16x16x32_f16(a, b, c, 0, 0, 0);
}

// gate+up, TM=64 TN=64 BK=64, 4 waves 2x2 (wave 32m x 32n), fused silu, PIPELINED.
// shared: blocks 0..255; routed gather: blocks 256..1023 (96 tiles x 8 nblk)
__global__ __launch_bounds__(256) void gu_all(
    const f16* __restrict__ xh,
    const float* __restrict__ sg, const float* __restrict__ su, f16* __restrict__ hsh,
    const float* __restrict__ wg, const float* __restrict__ wu, f16* __restrict__ hbuf,
    const int* __restrict__ t64_e, const int* __restrict__ t64_srow,
    const int* __restrict__ t64_hb, const int* __restrict__ ntl,
    const int* __restrict__ tok) {
  int b = blockIdx.x;
  const float *Bg, *Bu; f16* Hdst;
  int e = 0, srow = 0, mbase, n0, N;
  bool gather = (b >= 256);
  if (!gather) {
    Bg = sg; Bu = su; Hdst = hsh; N = ISH;
    mbase = (b >> 4) * 64; n0 = (b & 15) * 64;
  } else {
    int rb = b - 256, by = rb >> 3;
    if (by >= ntl[0]) return;
    e = t64_e[by]; srow = t64_srow[by]; mbase = t64_hb[by];
    size_t bo = (size_t)e * HDIM * IDIM;
    Bg = wg + bo; Bu = wu + bo; Hdst = hbuf; N = IDIM;
    n0 = (rb & 7) * 64;
  }
  const int K = HDIM, nk = HDIM / 64;

  __shared__ f16 As[2][64 * 64];               // 16 KB, double-buffered
  __shared__ f16 Bgs[64 * 72], Bus[64 * 72];   // 9 KB each

  int tid = threadIdx.x, lane = tid & 63, wave = tid >> 6;
  int quad = lane >> 4, l15 = lane & 15;
  int r = lane >> 3, p = lane & 7;

  // A staging: 8 gld16 (rows 0..63), 2 per wave
  const f16* gbA[2]; int lofA[2];
#pragma unroll
  for (int jj = 0; jj < 2; jj++) {
    int j = wave * 2 + jj;
    int kcol = (p ^ r) << 3;
    int row = j * 8 + r;
    int grow = gather ? tok[e * T_TOK + srow + row] : (mbase + row);
    gbA[jj] = xh + (size_t)grow * K + kcol;
    lofA[jj] = j << 9;
  }

  int wr = wave >> 1, wc = wave & 1;            // wave tile 32m x 32n
  f32x4 zero = {0.f, 0.f, 0.f, 0.f};
  f32x4 aG[2][2], aU[2][2];
#pragma unroll
  for (int mi = 0; mi < 2; mi++)
#pragma unroll
    for (int ni = 0; ni < 2; ni++) { aG[mi][ni] = zero; aU[mi][ni] = zero; }

  float2 vg[8], vu[8];
  // prologue: stage kt=0
  loadB(Bg, N, 0, n0, tid, vg);
  loadB(Bu, N, 0, n0, tid, vu);
#pragma unroll
  for (int jj = 0; jj < 2; jj++) gld16(gbA[jj], (f16*)As[0] + lofA[jj]);
  writeB(vg, Bgs, tid);
  writeB(vu, Bus, tid);
  barrier_full();

  for (int kt = 0; kt < nk; kt++) {
    int cur = kt & 1;
    bool more = (kt + 1 < nk);
    if (more) {                                  // prefetch kt+1: stays in flight
      loadB(Bg, N, (kt + 1) * 64, n0, tid, vg);
      loadB(Bu, N, (kt + 1) * 64, n0, tid, vu);
#pragma unroll
      for (int jj = 0; jj < 2; jj++)
        gld16(gbA[jj] + (kt + 1) * 64, (f16*)As[1 - cur] + lofA[jj]);
    }
    const f16* Ac = As[cur];
#pragma unroll
    for (int ks = 0; ks < 2; ks++) {
      int lch = (ks << 2) + quad;
      f16x8 a[2], g[2], u[2];
#pragma unroll
      for (int mi = 0; mi < 2; mi++) a[mi] = ldsfragA(Ac, 32 * wr + 16 * mi + l15, lch);
#pragma unroll
      for (int ni = 0; ni < 2; ni++) {
        g[ni] = ldsfragB(Bgs, 32 * wc + 16 * ni + l15, lch);
        u[ni] = ldsfragB(Bus, 32 * wc + 16 * ni + l15, lch);
      }
#pragma unroll
      for (int mi = 0; mi < 2; mi++)
#pragma unroll
        for (int ni = 0; ni < 2; ni++) {
          aG[mi][ni] = mfma16(a[mi], g[ni], aG[mi][ni]);
          aU[mi][ni] = mfma16(a[mi], u[ni], aU[mi][ni]);
        }
    }
    barrier_raw();                               // all waves done reading Bs (no drain)
    if (more) { writeB(vg, Bgs, tid); writeB(vu, Bus, tid); }
    barrier_full();                              // Bs + As[nxt] staged for kt+1
  }
#pragma unroll
  for (int mi = 0; mi < 2; mi++)
#pragma unroll
    for (int ni = 0; ni < 2; ni++)
#pragma unroll
      for (int rg = 0; rg < 4; rg++) {
        int m = 32 * wr + 16 * mi + (quad << 2) + rg;   // C/D: row = quad*4+reg
        int n = n0 + 32 * wc + 16 * ni + l15;           //      col = lane&15
        float g = aG[mi][ni][rg], u = aU[mi][ni][rg];
        float val = (g / (1.f + __expf(-g))) * u;
        Hdst[(size_t)(mbase + m) * N + n] = (f16)val;
      }
}

// down proj, TM=128 TN=64 BK=64, 4 waves 2x2 (wave 64m x 32n), PIPELINED.
// shared: blocks 0..127 -> out fp32; routed: blocks 128..895 -> odown f16
__global__ __launch_bounds__(256) void down_all(
    const f16* __restrict__ hsh, const float* __restrict__ sd,
    const f16* __restrict__ hbuf, const float* __restrict__ wd,
    float* __restrict__ out, f16* __restrict__ odown,
    const int* __restrict__ t128_e, const int* __restrict__ t128_hb,
    const int* __restrict__ ntl) {
  int b = blockIdx.x;
  bool routed = (b >= 128);
  const f16* A; const float* B; int K, abase, n0;
  if (!routed) {
    A = hsh; B = sd; K = ISH;
    abase = (b >> 4) * 128; n0 = (b & 15) * 64;
  } else {
    int rb = b - 128, by = rb >> 4;
    if (by >= ntl[1]) return;
    abase = t128_hb[by];
    A = hbuf; B = wd + (size_t)t128_e[by] * IDIM * HDIM; K = IDIM;
    n0 = (rb & 15) * 64;
  }
  const int nk = K / 64;

  __shared__ f16 As[2][128 * 64];       // 32 KB double-buffered
  __shared__ f16 Bs[64 * 72];           // 9 KB

  int tid = threadIdx.x, lane = tid & 63, wave = tid >> 6;
  int quad = lane >> 4, l15 = lane & 15;
  int r = lane >> 3, p = lane & 7;

  const f16* gbA[4]; int lofA[4];
#pragma unroll
  for (int jj = 0; jj < 4; jj++) {
    int j = wave * 4 + jj;
    int kcol = (p ^ r) << 3;
    int row = j * 8 + r;
    gbA[jj] = A + (size_t)(abase + row) * K + kcol;
    lofA[jj] = j << 9;
  }

  int wr = wave >> 1, wc = wave & 1;            // wave tile 64m x 32n
  f32x4 zero = {0.f, 0.f, 0.f, 0.f};
  f32x4 ac[4][2];
#pragma unroll
  for (int mi = 0; mi < 4; mi++)
#pragma unroll
    for (int ni = 0; ni < 2; ni++) ac[mi][ni] = zero;

  float2 vb[8];
  loadB(B, HDIM, 0, n0, tid, vb);
#pragma unroll
  for (int jj = 0; jj < 4; jj++) gld16(gbA[jj], (f16*)As[0] + lofA[jj]);
  writeB(vb, Bs, tid);
  barrier_full();

  for (int kt = 0; kt < nk; kt++) {
    int cur = kt & 1;
    bool more = (kt + 1 < nk);
    if (more) {
      loadB(B, HDIM, (kt + 1) * 64, n0, tid, vb);
#pragma unroll
      for (int jj = 0; jj < 4; jj++)
        gld16(gbA[jj] + (kt + 1) * 64, (f16*)As[1 - cur] + lofA[jj]);
    }
    const f16* Ac = As[cur];
#pragma unroll
    for (int ks = 0; ks < 2; ks++) {
      int lch = (ks << 2) + quad;
      f16x8 a[4], bb[2];
#pragma unroll
      for (int mi = 0; mi < 4; mi++) a[mi] = ldsfragA(Ac, 64 * wr + 16 * mi + l15, lch);
#pragma unroll
      for (int ni = 0; ni < 2; ni++) bb[ni] = ldsfragB(Bs, 32 * wc + 16 * ni + l15, lch);
#pragma unroll
      for (int mi = 0; mi < 4; mi++)
#pragma unroll
        for (int ni = 0; ni < 2; ni++)
          ac[mi][ni] = mfma16(a[mi], bb[ni], ac[mi][ni]);
    }
    barrier_raw();
    if (more) writeB(vb, Bs, tid);
    barrier_full();
  }
#pragma unroll
  for (int mi = 0; mi < 4; mi++)
#pragma unroll
    for (int ni = 0; ni < 2; ni++)
#pragma unroll
      for (int rg = 0; rg < 4; rg++) {
        int m = 64 * wr + 16 * mi + (quad << 2) + rg;
        int n = n0 + 32 * wc + 16 * ni + l15;
        if (routed) odown[(size_t)(abase + m) * HDIM + n] = (f16)ac[mi][ni][rg];
        else        out  [(size_t)(abase + m) * HDIM + n] = ac[mi][ni][rg];
      }
}

// =============== combine: out[t] += sum_j w_j * odown[slot(t,j)] ===============
__global__ __launch_bounds__(256) void combine_kernel(
    const f16* __restrict__ odown, const int* __restrict__ slotmap,
    const float* __restrict__ tkw, float* __restrict__ out) {
  int t = blockIdx.x;
  __shared__ int ss[4]; __shared__ float sw[4];
  if (threadIdx.x < 4) {
    ss[threadIdx.x] = slotmap[t * 4 + threadIdx.x];
    sw[threadIdx.x] = tkw[t * 4 + threadIdx.x];
  }
  __syncthreads();
  int h = threadIdx.x * 4;
  float4 acc = *(const float4*)(out + (size_t)t * HDIM + h);
#pragma unroll
  for (int j = 0; j < 4; j++) {
    f16x4 v = *(const f16x4*)(odown + (size_t)ss[j] * HDIM + h);
    float wj = sw[j];
    acc.x += wj * (float)v[0]; acc.y += wj * (float)v[1];
    acc.z += wj * (float)v[2]; acc.w += wj * (float)v[3];
  }
  *(float4*)(out + (size_t)t * HDIM + h) = acc;
}

// =============== launch ===============
extern "C" void kernel_launch(void* const* d_in, const int* in_sizes, int n_in,
                              void* d_out, int out_size, void* d_ws, size_t ws_size,
                              hipStream_t stream) {
  const float* x  = (const float*)d_in[0];
  const float* rw = (const float*)d_in[1];
  const float* eb = (const float*)d_in[2];
  const float* wg = (const float*)d_in[3];
  const float* wu = (const float*)d_in[4];
  const float* wd = (const float*)d_in[5];
  const float* sg = (const float*)d_in[6];
  const float* su = (const float*)d_in[7];
  const float* sd = (const float*)d_in[8];
  float* out = (float*)d_out;
  (void)in_sizes; (void)n_in; (void)out_size; (void)ws_size;

  char* w = (char*)d_ws;
  size_t off = 0;
  auto alloc = [&](size_t b) { void* p = w + off; off = (off + b + 255) & ~(size_t)255; return p; };

  f16* xh   = (f16*)alloc((size_t)T_TOK * HDIM * 2);
  f16* hbuf = (f16*)alloc((size_t)HSLOTS * IDIM * 2);
  f16* hsh  = (f16*)alloc((size_t)T_TOK * ISH * 2);
  f16* odown = (f16*)alloc((size_t)HSLOTS * HDIM * 2);
  int* topk_i = (int*)alloc((size_t)T_TOK * 4 * 4);
  float* topk_w = (float*)alloc((size_t)T_TOK * 4 * 4);
  int* tok  = (int*)alloc((size_t)NEXP * T_TOK * 4);
  int* slotmap = (int*)alloc((size_t)T_TOK * 4 * 4);
  int* t64_e  = (int*)alloc(MAXT64 * 4);
  int* t64_sr = (int*)alloc(MAXT64 * 4);
  int* t64_hb = (int*)alloc(MAXT64 * 4);
  int* t128_e  = (int*)alloc(MAXT128 * 4);
  int* t128_sr = (int*)alloc(MAXT128 * 4);
  int* t128_hb = (int*)alloc(MAXT128 * 4);
  int* ntl     = (int*)alloc(16);

  router_kernel<<<T_TOK / 4, 256, 0, stream>>>(x, rw, eb, xh, topk_i, topk_w);
  scatter_kernel<<<1, 1024, 0, stream>>>(topk_i, tok, slotmap,
                                         t64_e, t64_sr, t64_hb,
                                         t128_e, t128_sr, t128_hb, ntl);
  // shared gu (256) + routed gu (768) in one dispatch; pipelined K-loop
  gu_all<<<256 + MAXT64 * 8, 256, 0, stream>>>(
      xh, sg, su, hsh, wg, wu, hbuf, t64_e, t64_sr, t64_hb, ntl, tok);
  // shared down (128) -> out fp32; routed down (768) -> odown f16
  down_all<<<128 + MAXT128 * 16, 256, 0, stream>>>(
      hsh, sd, hbuf, wd, out, odown, t128_e, t128_hb, ntl);
  // out[t] += sum_j w_j * odown[slot]
  combine_kernel<<<T_TOK, 256, 0, stream>>>(odown, slotmap, topk_w, out);
}